// Round 22
// baseline (482.044 us; speedup 1.0000x reference)
//
#include <hip/hip_runtime.h>

#define HW 4096
#define CC 256
#define KK 2048
#define BB 16
#define NN (BB*HW)          // 65536
#define RPB 128             // rows per block

// d_out layout (floats): [z_q 16777216][idx 65536][loss 1][probs 134217728]
#define ZQ_SZ   (BB*CC*HW)
#define IDX_OFF ZQ_SZ
#define LOSS_OFF (IDX_OFF + NN)
#define PROBS_OFF (LOSS_OFF + 1)

// scratch parked in z_q region (float offsets), overwritten by k_zq at the end
#define EH_OFF 0            // eh[K][C] bf16 (rn) = 262144 floats
#define EE_OFF 262144       // ee_np[K] f32

#define TAU 0.01f
#define CAND_CAP 512
#define KTC 32              // codes per k-tile
#define KT_N 64             // tiles per pass
#define TB 16384            // bytes per tile

typedef short bf16x8 __attribute__((ext_vector_type(8)));
typedef float f32x16 __attribute__((ext_vector_type(16)));
typedef unsigned int u32;
typedef unsigned long long u64;

__device__ __forceinline__ void gload16(const void* g, void* l){
  __builtin_amdgcn_global_load_lds(
      (const __attribute__((address_space(1))) u32*)g,
      (__attribute__((address_space(3))) u32*)l, 16, 0, 0);
}

__device__ __forceinline__ unsigned short bf16rn(float x){
  unsigned u = __float_as_uint(x);
  return (unsigned short)((u + 0x7fffu + ((u >> 16) & 1u)) >> 16);
}

// counted-vmcnt barrier (uniform per-thread VMEM issue counts)
#define PBW(N) asm volatile("s_waitcnt vmcnt(" N ")\n\ts_barrier" ::: "memory");

// ---- numpy pairwise sum-of-squares over 256 elems (PW_BLOCKSIZE=128) ----
template<int STRIDE>
__device__ __forceinline__ float np_sumsq256(const float* __restrict__ a){
  float res0 = 0.f, res1 = 0.f;
  #pragma unroll
  for (int h = 0; h < 2; h++){
    const float* p = a + (size_t)h * 128 * STRIDE;
    float r[8];
    #pragma unroll
    for (int j = 0; j < 8; j++){ float x = p[(size_t)j * STRIDE]; r[j] = __fmul_rn(x, x); }
    for (int i = 8; i < 128; i += 8){
      #pragma unroll
      for (int j = 0; j < 8; j++){
        float x = p[(size_t)(i + j) * STRIDE];
        r[j] = __fadd_rn(r[j], __fmul_rn(x, x));
      }
    }
    float s = __fadd_rn(__fadd_rn(__fadd_rn(r[0], r[1]), __fadd_rn(r[2], r[3])),
                        __fadd_rn(__fadd_rn(r[4], r[5]), __fadd_rn(r[6], r[7])));
    if (h == 0) res0 = s; else res1 = s;
  }
  return __fadd_rn(res0, res1);
}

// ---------------- bf16(rn) conversion, coalesced ----------------
__global__ void k_cvt(const float* __restrict__ cb, float* __restrict__ out){
  const int i = blockIdx.x * 256 + threadIdx.x;   // 256 blocks; 8 channels each
  const int k = i >> 5, c8 = (i & 31) * 8;
  const float* row = cb + (size_t)k * CC + c8;
  unsigned short v[8];
  #pragma unroll
  for (int j = 0; j < 8; ++j) v[j] = bf16rn(row[j]);
  *(uint4*)((unsigned short*)(out + EH_OFF) + (size_t)k * CC + c8) = *(uint4*)v;
}

// ---------------- ee[k] = np-exact sum of squares ----------------
__global__ void k_ee(const float* __restrict__ cb, float* __restrict__ out){
  const int k = blockIdx.x * 256 + threadIdx.x;   // 8 blocks
  out[EE_OFF + k] = np_sumsq256<1>(cb + (size_t)k * CC);
}

// ---------------- main fused MFMA kernel: 128 rows x 2048 codes, 512 blocks ----------------
// 3-buf counted-vmcnt pipeline + deferred POST + setprio. KTC=32, 128 iterations.
__global__ __launch_bounds__(256, 2)
void k_mfma(const float* __restrict__ feats, const float* __restrict__ cb,
            float* __restrict__ out){
  __shared__ __align__(16) unsigned char lds_e[3 * TB];   // 49152 B
  __shared__ float ee_lds[KK];
  __shared__ unsigned long long rowkey[RPB];
  __shared__ int cand[CAND_CAP];
  __shared__ int cand_n;
  __shared__ float lsum;

  const int t = threadIdx.x;             // 256
  const int w = t >> 6, l = t & 63;
  const int grp = l >> 5;
  const int lane31 = l & 31;
  const int n0 = blockIdx.x * RPB;       // 512 blocks
  const int bi = n0 >> 12;
  const int hw0 = n0 & 4095;
  const int myhw = hw0 + w * 32 + lane31;

  for (int i = t; i < KK; i += 256) ee_lds[i] = out[EE_OFF + i];
  if (t < RPB) rowkey[t] = ~0ull;
  if (t == 0){ cand_n = 0; lsum = 0.f; }

  // ---- z fragments (B operand): z[c][myhw], resident in VGPRs
  bf16x8 ah0[16];
  {
    const float* zb = feats + (size_t)bi * CC * HW + myhw;
    #pragma unroll
    for (int cs = 0; cs < 16; ++cs){
      #pragma unroll
      for (int j = 0; j < 8; ++j)
        ah0[cs][j] = (short)bf16rn(zb[(size_t)(cs * 16 + grp * 8 + j) * HW]);
    }
  }

  const unsigned short* ehg = (const unsigned short*)(out + EH_OFF);

  // staging decode: ix = i*256+t -> cd=ix&31, g=(ix>>5)&1, cs=ix>>6 (4 chunks)
  int ofs_[4];
  #pragma unroll
  for (int i = 0; i < 4; ++i){
    int ix = i * 256 + t;
    int cd = ix & 31, g = (ix >> 5) & 1, cs = ix >> 6;
    ofs_[i] = cd * CC + cs * 16 + g * 8;
  }

#define STAGE(KT, BI) { \
    unsigned char* bb_ = lds_e + (size_t)(BI) * TB; \
    const unsigned short* tb_ = ehg + (size_t)(KT) * (KTC * CC); \
    _Pragma("unroll") \
    for (int i_ = 0; i_ < 4; ++i_) \
      gload16(tb_ + ofs_[i_], bb_ + (i_ * 256 + t) * 16); }

#define COMPUTE(BI, AA, AB) { \
    const unsigned char* hb_ = lds_e + (size_t)(BI) * TB; \
    _Pragma("unroll") \
    for (int ii = 0; ii < 16; ++ii){ AA[ii] = 0.f; AB[ii] = 0.f; } \
    __builtin_amdgcn_s_setprio(1); \
    _Pragma("unroll") \
    for (int cs = 0; cs < 16; ++cs){ \
      const unsigned char* bp_ = hb_ + (size_t)(cs * 2 + grp) * 512 + lane31 * 16; \
      bf16x8 e_ = *(const bf16x8*)(bp_); \
      if (cs & 1) AB = __builtin_amdgcn_mfma_f32_32x32x16_bf16(e_, ah0[cs], AB, 0, 0, 0); \
      else        AA = __builtin_amdgcn_mfma_f32_32x32x16_bf16(e_, ah0[cs], AA, 0, 0, 0); \
    } \
    __builtin_amdgcn_s_setprio(0); }

// POST of tile PKT (register sets PA,PB_): stats if PKT<64, else probs+cand
#define POST(PKT, PA, PB_) { \
    const int ptt = (PKT) & 63; \
    const int eebase = ptt * KTC + 4 * grp; \
    if ((PKT) < KT_N){ \
      _Pragma("unroll") \
      for (int r = 0; r < 16; ++r){ \
        int off = (r & 3) + 8 * (r >> 2); \
        float s = ee_lds[eebase + off] - 2.f * (PA[r] + PB_[r]); \
        m0 = fminf(m0, s); \
        ss0 += __expf(-s); \
      } \
    } else { \
      float* pb = out + (size_t)PROBS_OFF \
                + (size_t)(bi * KK + eebase) * HW + myhw; \
      _Pragma("unroll") \
      for (int r = 0; r < 16; ++r){ \
        int off = (r & 3) + 8 * (r >> 2); \
        float s = ee_lds[eebase + off] - 2.f * (PA[r] + PB_[r]); \
        pb[(size_t)off * HW] = __expf(-s) * inv0; \
        if (s <= m0 + TAU){ \
          int sl = atomicAdd(&cand_n, 1); \
          if (sl < CAND_CAP) cand[sl] = ((w * 32 + lane31) << 16) | (eebase + off); \
        } \
      } \
    } }

// counted wait: pass1 leaves stage(kt+2)=4; pass2 leaves stores(kt-1)+stage(kt+2)=20
#define PBSEL(KT) { \
    if ((KT) >= 125)      { PBW("0") } \
    else if ((KT) <= 64)  { PBW("4") } \
    else                  { PBW("20") } }

  f32x16 aA0, aB0, aA1, aB1;
  float m0 = 3e38f, ss0 = 0.f, inv0 = 0.f;

  STAGE(0, 0);
  STAGE(1, 1);
  PBW("4")                              // retire stage(0); stage(1) in flight

  // 128 iterations, 2x-unrolled for static accumulator parity
  for (int kt2 = 0; kt2 < KT_N; ++kt2){
    const int ktA = 2 * kt2;
    {
      if (ktA <= 125) STAGE((ktA + 2) & 63, (ktA + 2) % 3);
      if (ktA > 0) POST(ktA - 1, aA1, aB1);
      if (ktA == KT_N){                 // after POST(63): finalize stats
        m0 = fminf(m0, __shfl_xor(m0, 32));
        ss0 += __shfl_xor(ss0, 32);
        inv0 = 1.f / ss0;
      }
      COMPUTE(ktA % 3, aA0, aB0);
      PBSEL(ktA)
    }
    {
      const int ktB = ktA + 1;
      if (ktB <= 125) STAGE((ktB + 2) & 63, (ktB + 2) % 3);
      POST(ktB - 1, aA0, aB0);
      COMPUTE(ktB % 3, aA1, aB1);
      PBSEL(ktB)
    }
  }
  POST(2 * KT_N - 1, aA1, aB1);         // tile 63 of probs pass
  __syncthreads();

  // ---- bit-exact rescore of candidates (numpy fp32 chain, zz on demand)
  int nc = cand_n; if (nc > CAND_CAP) nc = CAND_CAP;
  for (int i = t; i < nc; i += 256){
    int rc = cand[i];
    int rl = (rc >> 16) & 127, code = rc & 2047;
    int n = n0 + rl;
    const float* zp = feats + (size_t)(n >> 12) * CC * HW + (n & 4095);
    const float* ep = cb + (size_t)code * CC;
    float a = 0.f;
    #pragma unroll 8
    for (int c = 0; c < CC; ++c) a = __builtin_fmaf(zp[(size_t)c * HW], ep[c], a);
    float zzv = np_sumsq256<HW>(zp);
    float t1 = __fadd_rn(zzv, ee_lds[code]);
    float d = __fadd_rn(t1, -2.f * a);
    unsigned long long key = ((unsigned long long)__float_as_uint(d) << 32) | (unsigned)code;
    atomicMin(&rowkey[rl], key);
  }
  __syncthreads();

  if (t < RPB) out[IDX_OFF + n0 + t] = (float)(int)(rowkey[t] & 2047u);

  // ---- loss: threads 0..127 each handle one row
  if (t < RPB){
    int code = (int)(rowkey[t] & 2047u);
    const float* ep = cb + (size_t)code * CC;
    const float* zp = feats + (size_t)bi * CC * HW + hw0 + t;
    float s = 0.f;
    for (int c = 0; c < CC; ++c){
      float dz = ep[c] - zp[(size_t)c * HW];
      s = __builtin_fmaf(dz, dz, s);
    }
    atomicAdd(&lsum, s);
  }
  __syncthreads();
  if (t == 0) atomicAdd(out + LOSS_OFF, lsum * (1.25f / 16777216.f));
}

// ---------------- z_q gather (bit-exact copy; overwrites scratch) ----------------
__global__ void k_zq(const float* __restrict__ cb, float* __restrict__ out){
  const int f4 = blockIdx.x * 256 + threadIdx.x;  // 16384 blocks
  const int f = f4 * 4;
  const int b = f >> 20;
  const int rem = f & 1048575;
  const int c = rem >> 12;
  const int hw = rem & 4095;
  const int n = b * HW + hw;
  const float* idxf = out + IDX_OFF;
  float4 iv = *(const float4*)(idxf + n);
  float4 o;
  o.x = cb[(size_t)((int)iv.x) * CC + c];
  o.y = cb[(size_t)((int)iv.y) * CC + c];
  o.z = cb[(size_t)((int)iv.z) * CC + c];
  o.w = cb[(size_t)((int)iv.w) * CC + c];
  *(float4*)(out + f) = o;
}

extern "C" void kernel_launch(void* const* d_in, const int* in_sizes, int n_in,
                              void* d_out, int out_size, void* d_ws, size_t ws_size,
                              hipStream_t stream){
  const float* feats = (const float*)d_in[0];
  const float* cb    = (const float*)d_in[1];
  float* out = (float*)d_out;

  (void)hipMemsetAsync(out + LOSS_OFF, 0, sizeof(float), stream);
  hipLaunchKernelGGL(k_cvt,  dim3(256),   dim3(256), 0, stream, cb, out);
  hipLaunchKernelGGL(k_ee,   dim3(8),     dim3(256), 0, stream, cb, out);
  hipLaunchKernelGGL(k_mfma, dim3(512),   dim3(256), 0, stream, feats, cb, out);
  hipLaunchKernelGGL(k_zq,   dim3(16384), dim3(256), 0, stream, cb, out);
}

// Round 23
// 461.369 us; speedup vs baseline: 1.0448x; 1.0448x over previous
//
#include <hip/hip_runtime.h>

#define HW 4096
#define CC 256
#define KK 2048
#define BB 16
#define NN (BB*HW)          // 65536
#define RPB 128             // rows per block

// d_out layout (floats): [z_q 16777216][idx 65536][loss 1][probs 134217728]
#define ZQ_SZ   (BB*CC*HW)
#define IDX_OFF ZQ_SZ
#define LOSS_OFF (IDX_OFF + NN)
#define PROBS_OFF (LOSS_OFF + 1)

// scratch parked in z_q region (float offsets), overwritten by k_zq at the end
#define EH_OFF 0            // eh[K][C] bf16 (rn) = 262144 floats
#define EE_OFF 262144       // ee_np[K] f32

#define TAU 0.01f
#define CAND_CAP 512
#define KTC 64              // codes per k-tile
#define KT_N 32             // tiles per pass

typedef short bf16x8 __attribute__((ext_vector_type(8)));
typedef float f32x16 __attribute__((ext_vector_type(16)));
typedef unsigned int u32;
typedef unsigned long long u64;

__device__ __forceinline__ void gload16(const void* g, void* l){
  __builtin_amdgcn_global_load_lds(
      (const __attribute__((address_space(1))) u32*)g,
      (__attribute__((address_space(3))) u32*)l, 16, 0, 0);
}

__device__ __forceinline__ unsigned short bf16rn(float x){
  unsigned u = __float_as_uint(x);
  return (unsigned short)((u + 0x7fffu + ((u >> 16) & 1u)) >> 16);
}

// ---- numpy pairwise sum-of-squares over 256 elems (PW_BLOCKSIZE=128) ----
template<int STRIDE>
__device__ __forceinline__ float np_sumsq256(const float* __restrict__ a){
  float res0 = 0.f, res1 = 0.f;
  #pragma unroll
  for (int h = 0; h < 2; h++){
    const float* p = a + (size_t)h * 128 * STRIDE;
    float r[8];
    #pragma unroll
    for (int j = 0; j < 8; j++){ float x = p[(size_t)j * STRIDE]; r[j] = __fmul_rn(x, x); }
    for (int i = 8; i < 128; i += 8){
      #pragma unroll
      for (int j = 0; j < 8; j++){
        float x = p[(size_t)(i + j) * STRIDE];
        r[j] = __fadd_rn(r[j], __fmul_rn(x, x));
      }
    }
    float s = __fadd_rn(__fadd_rn(__fadd_rn(r[0], r[1]), __fadd_rn(r[2], r[3])),
                        __fadd_rn(__fadd_rn(r[4], r[5]), __fadd_rn(r[6], r[7])));
    if (h == 0) res0 = s; else res1 = s;
  }
  return __fadd_rn(res0, res1);
}

// ---------------- bf16(rn) conversion, coalesced ----------------
__global__ void k_cvt(const float* __restrict__ cb, float* __restrict__ out){
  const int i = blockIdx.x * 256 + threadIdx.x;   // 256 blocks; 8 channels each
  const int k = i >> 5, c8 = (i & 31) * 8;
  const float* row = cb + (size_t)k * CC + c8;
  unsigned short v[8];
  #pragma unroll
  for (int j = 0; j < 8; ++j) v[j] = bf16rn(row[j]);
  *(uint4*)((unsigned short*)(out + EH_OFF) + (size_t)k * CC + c8) = *(uint4*)v;
}

// ---------------- ee[k] = np-exact sum of squares ----------------
__global__ void k_ee(const float* __restrict__ cb, float* __restrict__ out){
  const int k = blockIdx.x * 256 + threadIdx.x;   // 8 blocks
  out[EE_OFF + k] = np_sumsq256<1>(cb + (size_t)k * CC);
}

// ---------------- main fused MFMA kernel: 128 rows x 2048 codes, 512 blocks ----------------
// lds_e[buf][cs 16][grp 2][code 64][16B]; mfma(e, z) -> D[code][zrow]
// Deferred POST: iteration kt runs POST(kt-1) (VALU) alongside COMPUTE(kt) (MFMA).
__global__ __launch_bounds__(256, 2)
void k_mfma(const float* __restrict__ feats, const float* __restrict__ cb,
            float* __restrict__ out){
  __shared__ __align__(16) unsigned char lds_e[2][32768];
  __shared__ float ee_lds[KK];
  __shared__ unsigned long long rowkey[RPB];
  __shared__ int cand[CAND_CAP];
  __shared__ int cand_n;
  __shared__ float lsum;

  const int t = threadIdx.x;             // 256
  const int w = t >> 6, l = t & 63;
  const int grp = l >> 5;
  const int lane31 = l & 31;
  const int n0 = blockIdx.x * RPB;       // 512 blocks
  const int bi = n0 >> 12;
  const int hw0 = n0 & 4095;
  const int myhw = hw0 + w * 32 + lane31;

  for (int i = t; i < KK; i += 256) ee_lds[i] = out[EE_OFF + i];
  if (t < RPB) rowkey[t] = ~0ull;
  if (t == 0){ cand_n = 0; lsum = 0.f; }

  // ---- z fragments (B operand): z[c][myhw], resident in VGPRs
  bf16x8 ah0[16];
  {
    const float* zb = feats + (size_t)bi * CC * HW + myhw;
    #pragma unroll
    for (int cs = 0; cs < 16; ++cs){
      #pragma unroll
      for (int j = 0; j < 8; ++j)
        ah0[cs][j] = (short)bf16rn(zb[(size_t)(cs * 16 + grp * 8 + j) * HW]);
    }
  }

  const unsigned short* ehg = (const unsigned short*)(out + EH_OFF);

  // per-thread source element offsets for the 8 staging chunks (32KB tile)
  int ofs_[8];
  #pragma unroll
  for (int i = 0; i < 8; ++i){
    int ix = i * 256 + t;
    int cd = ix & 63, g = (ix >> 6) & 1, cs = ix >> 7;
    ofs_[i] = cd * CC + cs * 16 + g * 8;
  }

#define STAGE(KT, B) { \
    const unsigned short* tb_ = ehg + (size_t)(KT) * (KTC * CC); \
    _Pragma("unroll") \
    for (int i_ = 0; i_ < 8; ++i_) \
      gload16(tb_ + ofs_[i_], &lds_e[B][(i_ * 256 + t) * 16]); }

#define COMPUTE(B, AA, AB) { \
    _Pragma("unroll") \
    for (int ii = 0; ii < 16; ++ii){ AA[ii] = 0.f; AB[ii] = 0.f; } \
    _Pragma("unroll") \
    for (int cs = 0; cs < 16; ++cs){ \
      const unsigned char* bp_ = &lds_e[B][(size_t)(cs * 2 + grp) * 1024 + lane31 * 16]; \
      bf16x8 e0_ = *(const bf16x8*)(bp_); \
      bf16x8 e1_ = *(const bf16x8*)(bp_ + 512); \
      AA = __builtin_amdgcn_mfma_f32_32x32x16_bf16(e0_, ah0[cs], AA, 0, 0, 0); \
      AB = __builtin_amdgcn_mfma_f32_32x32x16_bf16(e1_, ah0[cs], AB, 0, 0, 0); \
    } }

// POST of tile PKT using register set (PA,PB_); stats if PKT<32 else probs+cand
#define POST(PKT, PA, PB_) { \
    const int ptt = (PKT) & 31; \
    const int eebase = ptt * 64 + 4 * grp; \
    if ((PKT) < KT_N){ \
      _Pragma("unroll") \
      for (int r = 0; r < 16; ++r){ \
        int off = (r & 3) + 8 * (r >> 2); \
        float s0 = ee_lds[eebase + off]      - 2.f * PA[r]; \
        float s1 = ee_lds[eebase + off + 32] - 2.f * PB_[r]; \
        m0 = fminf(m0, fminf(s0, s1)); \
        ss0 += __expf(-s0) + __expf(-s1); \
      } \
    } else { \
      float* pb = out + (size_t)PROBS_OFF \
                + (size_t)(bi * KK + ptt * 64 + 4 * grp) * HW + myhw; \
      _Pragma("unroll") \
      for (int r = 0; r < 16; ++r){ \
        int off = (r & 3) + 8 * (r >> 2); \
        float s0 = ee_lds[eebase + off]      - 2.f * PA[r]; \
        float s1 = ee_lds[eebase + off + 32] - 2.f * PB_[r]; \
        float* p = pb + (size_t)off * HW; \
        p[0]               = __expf(-s0) * inv0; \
        p[(size_t)32 * HW] = __expf(-s1) * inv0; \
        int cg = eebase + off; \
        if (s0 <= m0 + TAU){ \
          int sl = atomicAdd(&cand_n, 1); \
          if (sl < CAND_CAP) cand[sl] = ((w * 32 + lane31) << 16) | cg; \
        } \
        if (s1 <= m0 + TAU){ \
          int sl = atomicAdd(&cand_n, 1); \
          if (sl < CAND_CAP) cand[sl] = ((w * 32 + lane31) << 16) | (cg + 32); \
        } \
      } \
    } }

  f32x16 aA0, aB0, aA1, aB1;
  float m0 = 3e38f, ss0 = 0.f, inv0 = 0.f;

  STAGE(0, 0);
  __syncthreads();

  // fused loop, 2x-unrolled so accumulator-set selection is compile-time
  for (int kt2 = 0; kt2 < KT_N; ++kt2){
    const int ktA = 2 * kt2;          // even step: compute set0, post set1
    {
      STAGE((ktA + 1) & 31, 1);       // buf = ktA&1 = 0 -> stage into 1
      if (ktA > 0) POST(ktA - 1, aA1, aB1);
      if (ktA == KT_N){               // after POST(31): finalize stats
        m0 = fminf(m0, __shfl_xor(m0, 32));
        ss0 += __shfl_xor(ss0, 32);
        inv0 = 1.f / ss0;
      }
      COMPUTE(0, aA0, aB0);
      __syncthreads();
    }
    {
      const int ktB = ktA + 1;        // odd step: compute set1, post set0
      if (ktB < 2 * KT_N - 1) STAGE((ktB + 1) & 31, 0);
      POST(ktB - 1, aA0, aB0);
      COMPUTE(1, aA1, aB1);
      __syncthreads();
    }
  }
  POST(2 * KT_N - 1, aA1, aB1);       // tile 63 (probs)
  __syncthreads();

  // ---- bit-exact rescore of candidates (numpy fp32 chain, zz on demand)
  int nc = cand_n; if (nc > CAND_CAP) nc = CAND_CAP;
  for (int i = t; i < nc; i += 256){
    int rc = cand[i];
    int rl = (rc >> 16) & 127, code = rc & 2047;
    int n = n0 + rl;
    const float* zp = feats + (size_t)(n >> 12) * CC * HW + (n & 4095);
    const float* ep = cb + (size_t)code * CC;
    float a = 0.f;
    #pragma unroll 8
    for (int c = 0; c < CC; ++c) a = __builtin_fmaf(zp[(size_t)c * HW], ep[c], a);
    float zzv = np_sumsq256<HW>(zp);
    float t1 = __fadd_rn(zzv, ee_lds[code]);
    float d = __fadd_rn(t1, -2.f * a);
    unsigned long long key = ((unsigned long long)__float_as_uint(d) << 32) | (unsigned)code;
    atomicMin(&rowkey[rl], key);
  }
  __syncthreads();

  if (t < RPB) out[IDX_OFF + n0 + t] = (float)(int)(rowkey[t] & 2047u);

  // ---- loss: threads 0..127 each handle one row
  if (t < RPB){
    int code = (int)(rowkey[t] & 2047u);
    const float* ep = cb + (size_t)code * CC;
    const float* zp = feats + (size_t)bi * CC * HW + hw0 + t;
    float s = 0.f;
    for (int c = 0; c < CC; ++c){
      float dz = ep[c] - zp[(size_t)c * HW];
      s = __builtin_fmaf(dz, dz, s);
    }
    atomicAdd(&lsum, s);
  }
  __syncthreads();
  if (t == 0) atomicAdd(out + LOSS_OFF, lsum * (1.25f / 16777216.f));
}

// ---------------- z_q gather (bit-exact copy; overwrites scratch) ----------------
__global__ void k_zq(const float* __restrict__ cb, float* __restrict__ out){
  const int f4 = blockIdx.x * 256 + threadIdx.x;  // 16384 blocks
  const int f = f4 * 4;
  const int b = f >> 20;
  const int rem = f & 1048575;
  const int c = rem >> 12;
  const int hw = rem & 4095;
  const int n = b * HW + hw;
  const float* idxf = out + IDX_OFF;
  float4 iv = *(const float4*)(idxf + n);
  float4 o;
  o.x = cb[(size_t)((int)iv.x) * CC + c];
  o.y = cb[(size_t)((int)iv.y) * CC + c];
  o.z = cb[(size_t)((int)iv.z) * CC + c];
  o.w = cb[(size_t)((int)iv.w) * CC + c];
  *(float4*)(out + f) = o;
}

extern "C" void kernel_launch(void* const* d_in, const int* in_sizes, int n_in,
                              void* d_out, int out_size, void* d_ws, size_t ws_size,
                              hipStream_t stream){
  const float* feats = (const float*)d_in[0];
  const float* cb    = (const float*)d_in[1];
  float* out = (float*)d_out;

  (void)hipMemsetAsync(out + LOSS_OFF, 0, sizeof(float), stream);
  hipLaunchKernelGGL(k_cvt,  dim3(256),   dim3(256), 0, stream, cb, out);
  hipLaunchKernelGGL(k_ee,   dim3(8),     dim3(256), 0, stream, cb, out);
  hipLaunchKernelGGL(k_mfma, dim3(512),   dim3(256), 0, stream, feats, cb, out);
  hipLaunchKernelGGL(k_zq,   dim3(16384), dim3(256), 0, stream, cb, out);
}